// Round 3
// baseline (84.113 us; speedup 1.0000x reference)
//
#include <hip/hip_runtime.h>
#include <math.h>

#define NR   2048
#define XD   512
#define HID  300
#define BS   256
#define NCH  8
#define NPAD 320          // HID padded to 32
#define KTOT 1024
#define GSTR 304          // row stride for GPB/P0a/P0b (float4-aligned)
#define NBLK 576          // fused grid = 64 x 9

typedef __attribute__((ext_vector_type(8))) short bf16x8;
typedef __attribute__((ext_vector_type(4))) float f32x4;

__device__ __forceinline__ float softplus_f(float x) {
    return fmaxf(x, 0.f) + log1pf(__expf(-fabsf(x)));
}
__device__ __forceinline__ unsigned short f2bf(float f) {
    unsigned int u = __float_as_uint(f);
    u += 0x7FFFu + ((u >> 16) & 1u);   // RNE
    return (unsigned short)(u >> 16);
}

// grid.x = 2048 (Aneg rows) + 2048 (Apos rows) + 320 (Wt tiles)
__global__ __launch_bounds__(256) void convert(
    const float* __restrict__ pl, const float* __restrict__ pg,
    const float* __restrict__ nl, const float* __restrict__ ng,
    const float* __restrict__ W1,
    unsigned short* __restrict__ Aneg, unsigned short* __restrict__ Apos,
    unsigned short* __restrict__ Wt, unsigned int* __restrict__ counter)
{
    const int b = blockIdx.x, tid = threadIdx.x;
    if (b == 0 && tid == 0) *counter = 0u;   // reset ticket each call
    if (b < 4096) {
        const int m = (b < 2048) ? b : b - 2048;
        const float* lo = (b < 2048) ? nl : pl;
        const float* hi = (b < 2048) ? ng : pg;
        unsigned short* dst = (b < 2048) ? Aneg : Apos;
        const int kq = tid * 4;
        const float4 v = (kq < XD) ? *(const float4*)(lo + m * XD + kq)
                                   : *(const float4*)(hi + m * XD + kq - XD);
        ushort4 o;
        o.x = f2bf(v.x); o.y = f2bf(v.y); o.z = f2bf(v.z); o.w = f2bf(v.w);
        *(ushort4*)(dst + m * KTOT + kq) = o;
    } else {
        // W1 [1024][300] -> Wt [320][1024] bf16, zero-padded rows 300..319
        __shared__ unsigned short ts[16][72];
        const int t = b - 4096;
        const int nt = t % 20, kt = t / 20;   // 20 n-tiles x 16 k-tiles
        const int n = nt * 16 + (tid & 15);
        const int kl = tid >> 4;
        #pragma unroll
        for (int j = 0; j < 4; ++j) {
            const int k = kt * 64 + kl * 4 + j;
            const float val = (n < HID) ? W1[k * HID + n] : 0.f;
            ts[tid & 15][kl * 4 + j] = f2bf(val);
        }
        __syncthreads();
        const int nw = tid >> 4, kw = (tid & 15) * 4;
        ushort4 o;
        o.x = ts[nw][kw]; o.y = ts[nw][kw + 1]; o.z = ts[nw][kw + 2]; o.w = ts[nw][kw + 3];
        *(ushort4*)(Wt + (nt * 16 + nw) * KTOT + kt * 64 + kw) = o;
    }
}

// One wave per block, 32x32 tile of 16x16x32 MFMAs, all jobs K=512.
// job 0: LP4  = nl @ W1l               (k<512,  scattered [k/4][l][4])
// job 1: GPB  = ng @ W1g + b1          (k>=512)
// job 2: P0a  = pl @ W1l               (k<512,  raw)
// job 3: P0b  = pg @ W1g               (k>=512, raw)
__global__ __launch_bounds__(64) void mfma_gemm(
    const unsigned short* __restrict__ Aneg, const unsigned short* __restrict__ Apos,
    const unsigned short* __restrict__ Wt, const float* __restrict__ b1,
    float* __restrict__ LP4, float* __restrict__ GPB,
    float* __restrict__ P0a, float* __restrict__ P0b)
{
    const int job = blockIdx.z;
    const int m0 = blockIdx.x * 32, n0 = blockIdx.y * 32;
    const int lane = threadIdx.x;
    const int r = lane & 15, g = lane >> 4;

    const unsigned short* A = (job >= 2) ? Apos : Aneg;
    const int kbeg = (job & 1) ? XD : 0;

    const unsigned short* a0p = A  + (m0 + r) * KTOT + kbeg + 8 * g;
    const unsigned short* a1p = a0p + 16 * KTOT;
    const unsigned short* b0p = Wt + (n0 + r) * KTOT + kbeg + 8 * g;
    const unsigned short* b1p = b0p + 16 * KTOT;

    f32x4 acc00 = {0,0,0,0}, acc01 = {0,0,0,0}, acc10 = {0,0,0,0}, acc11 = {0,0,0,0};

    #pragma unroll 8
    for (int k = 0; k < XD; k += 32) {
        const bf16x8 a0 = *(const bf16x8*)(a0p + k);
        const bf16x8 a1 = *(const bf16x8*)(a1p + k);
        const bf16x8 w0 = *(const bf16x8*)(b0p + k);
        const bf16x8 w1 = *(const bf16x8*)(b1p + k);
        acc00 = __builtin_amdgcn_mfma_f32_16x16x32_bf16(a0, w0, acc00, 0, 0, 0);
        acc01 = __builtin_amdgcn_mfma_f32_16x16x32_bf16(a0, w1, acc01, 0, 0, 0);
        acc10 = __builtin_amdgcn_mfma_f32_16x16x32_bf16(a1, w0, acc10, 0, 0, 0);
        acc11 = __builtin_amdgcn_mfma_f32_16x16x32_bf16(a1, w1, acc11, 0, 0, 0);
    }

    f32x4 accs[2][2] = {{acc00, acc01}, {acc10, acc11}};
    #pragma unroll
    for (int mi = 0; mi < 2; ++mi) {
        #pragma unroll
        for (int ni = 0; ni < 2; ++ni) {
            const int n = n0 + ni * 16 + r;
            const int mb = m0 + mi * 16 + 4 * g;
            const f32x4 v = accs[mi][ni];
            if (job == 0) {
                float* base = LP4 + ((size_t)(n >> 2) * NR + mb) * 4 + (n & 3);
                base[0] = v[0]; base[4] = v[1]; base[8] = v[2]; base[12] = v[3];
            } else if (n < HID) {
                const float bias = (job == 1) ? b1[n] : 0.f;
                float* out = (job == 1) ? GPB : ((job == 2) ? P0a : P0b);
                #pragma unroll
                for (int j = 0; j < 4; ++j)
                    out[(size_t)(mb + j) * GSTR + n] = v[j] + bias;
            }
        }
    }
}

// grid (64, 9): y<8 -> neg chunk=y, g-group=x ; y==8 && x<8 -> pos rows x*256
// Last block (ticket) sums all partials -> out.
__global__ __launch_bounds__(256) void fused(
    const float* __restrict__ LP4, const float* __restrict__ GPB,
    const float* __restrict__ P0a, const float* __restrict__ P0b,
    const float* __restrict__ b1, const float* __restrict__ W2,
    const float* __restrict__ b2,
    float* __restrict__ partials, unsigned int* __restrict__ counter,
    float* __restrict__ out)
{
    __shared__ float gbs[4][HID];
    __shared__ float w2s[HID];
    __shared__ float red[4][4];
    __shared__ int sh_last;
    const int tid = threadIdx.x;
    const int bx = blockIdx.x, by = blockIdx.y;
    const int bid = by * 64 + bx;
    const int wid = tid >> 6;
    float partial = 0.f;

    if (by < 8) {
        const int chunk = by, g0 = bx * 4;
        for (int idx = tid; idx < 4 * HID; idx += 256) {
            const int gt = idx / HID, k = idx - gt * HID;
            gbs[gt][k] = GPB[(size_t)(chunk * BS + g0 + gt) * GSTR + k];
        }
        for (int idx = tid; idx < HID; idx += 256) w2s[idx] = W2[idx];
        __syncthreads();

        const int lg = chunk * BS + tid;
        const float4* lp4 = (const float4*)LP4 + lg;
        float acc[4] = {0.f, 0.f, 0.f, 0.f};
        for (int k4 = 0; k4 < HID / 4; ++k4) {
            const float4 lp = lp4[(size_t)k4 * NR];
            const float4 w4 = *(const float4*)&w2s[k4 * 4];
            #pragma unroll
            for (int gt = 0; gt < 4; ++gt) {
                const float4 g4 = *(const float4*)&gbs[gt][k4 * 4];
                acc[gt] = fmaf(fmaxf(g4.x + lp.x, 0.f), w4.x, acc[gt]);
                acc[gt] = fmaf(fmaxf(g4.y + lp.y, 0.f), w4.y, acc[gt]);
                acc[gt] = fmaf(fmaxf(g4.z + lp.z, 0.f), w4.z, acc[gt]);
                acc[gt] = fmaf(fmaxf(g4.w + lp.w, 0.f), w4.w, acc[gt]);
            }
        }

        const float b2v = b2[0];
        // s bounded (~<10 here) -> exp never overflows; LSE without max-subtract.
        #pragma unroll
        for (int gt = 0; gt < 4; ++gt) {
            float e = __expf(softplus_f(acc[gt] + b2v));
            #pragma unroll
            for (int o = 32; o > 0; o >>= 1) e += __shfl_xor(e, o);
            if ((tid & 63) == 0) red[wid][gt] = e;
        }
        __syncthreads();
        partial = 0.f;
        #pragma unroll
        for (int gt = 0; gt < 4; ++gt)
            partial += __logf(red[0][gt] + red[1][gt] + red[2][gt] + red[3][gt]);
    } else if (bx < 8) {
        // pos: rows bx*256 + tid ; P0 = P0a + P0b + b1
        for (int idx = tid; idx < HID; idx += 256) {
            w2s[idx] = W2[idx];
            gbs[0][idx] = b1[idx];
        }
        __syncthreads();
        const int i = bx * 256 + tid;
        const float4* ra = (const float4*)(P0a + (size_t)i * GSTR);
        const float4* rb = (const float4*)(P0b + (size_t)i * GSTR);
        float acc = 0.f;
        for (int q = 0; q < HID / 4; ++q) {
            const float4 a = ra[q], b = rb[q];
            const float4 bb = *(const float4*)&gbs[0][q * 4];
            const float4 wv = *(const float4*)&w2s[q * 4];
            acc += fmaxf(a.x + b.x + bb.x, 0.f) * wv.x
                 + fmaxf(a.y + b.y + bb.y, 0.f) * wv.y
                 + fmaxf(a.z + b.z + bb.z, 0.f) * wv.z
                 + fmaxf(a.w + b.w + bb.w, 0.f) * wv.w;
        }
        float sp = softplus_f(acc + b2[0]);
        #pragma unroll
        for (int o = 32; o > 0; o >>= 1) sp += __shfl_xor(sp, o);
        if ((tid & 63) == 0) red[wid][0] = sp;
        __syncthreads();
        partial = -(red[0][0] + red[1][0] + red[2][0] + red[3][0]);
    }

    // ---- last-block finalize (device-scope ticket) ----
    if (tid == 0) {
        partials[bid] = partial;
        __threadfence();
        const unsigned t = atomicAdd(counter, 1u);
        sh_last = (t == NBLK - 1) ? 1 : 0;
    }
    __syncthreads();
    if (sh_last) {
        __threadfence();
        const volatile float* p = (const volatile float*)partials;
        float v = p[tid] + p[tid + 256];
        if (tid + 512 < NBLK) v += p[tid + 512];
        #pragma unroll
        for (int o = 32; o > 0; o >>= 1) v += __shfl_xor(v, o);
        if ((tid & 63) == 0) red[wid][0] = v;
        __syncthreads();
        if (tid == 0)
            out[0] = (red[0][0] + red[1][0] + red[2][0] + red[3][0]) * (1.f / 2048.f);
    }
}

extern "C" void kernel_launch(void* const* d_in, const int* in_sizes, int n_in,
                              void* d_out, int out_size, void* d_ws, size_t ws_size,
                              hipStream_t stream)
{
    const float* pl = (const float*)d_in[0];
    const float* pg = (const float*)d_in[1];
    const float* nl = (const float*)d_in[2];
    const float* ng = (const float*)d_in[3];
    const float* W1 = (const float*)d_in[4];
    const float* b1 = (const float*)d_in[5];
    const float* W2 = (const float*)d_in[6];
    const float* b2 = (const float*)d_in[7];

    char* ws = (char*)d_ws;
    unsigned short* Aneg = (unsigned short*)(ws);                 // 4 MB
    unsigned short* Apos = (unsigned short*)(ws + (4u << 20));    // 4 MB
    unsigned short* Wt   = (unsigned short*)(ws + (8u << 20));    // 640 KB
    float* LP4  = (float*)(ws + (9u << 20));                      // 2.62 MB
    float* GPB  = (float*)(ws + (12u << 20));                     // 2.49 MB
    float* P0a  = (float*)(ws + (15u << 20));                     // 2.49 MB
    float* P0b  = (float*)(ws + (18u << 20));                     // 2.49 MB
    float* partials = (float*)(ws + (21u << 20));                 // 576 f
    unsigned int* counter = (unsigned int*)(ws + (21u << 20) + 4096);
    float* out = (float*)d_out;

    hipLaunchKernelGGL(convert, dim3(4096 + 320), dim3(256), 0, stream,
                       pl, pg, nl, ng, W1, Aneg, Apos, Wt, counter);
    hipLaunchKernelGGL(mfma_gemm, dim3(NR / 32, NPAD / 32, 4), dim3(64), 0, stream,
                       Aneg, Apos, Wt, b1, LP4, GPB, P0a, P0b);
    hipLaunchKernelGGL(fused, dim3(64, 9), dim3(256), 0, stream,
                       LP4, GPB, P0a, P0b, b1, W2, b2, partials, counter, out);
}

// Round 4
// 79.830 us; speedup vs baseline: 1.0537x; 1.0537x over previous
//
#include <hip/hip_runtime.h>
#include <math.h>

#define NR   2048
#define XD   512
#define HID  300
#define BS   256
#define NCH  8
#define NPAD 320          // HID padded to 32
#define KTOT 1024
#define GSTR 304          // row stride for GPB/P0a/P0b (float4-aligned)
#define NBLK 288          // fused grid = 32 x 9

typedef __attribute__((ext_vector_type(8))) short bf16x8;
typedef __attribute__((ext_vector_type(4))) float f32x4;

__device__ __forceinline__ float softplus_f(float x) {
    return fmaxf(x, 0.f) + log1pf(__expf(-fabsf(x)));
}
__device__ __forceinline__ unsigned short f2bf(float f) {
    unsigned int u = __float_as_uint(f);
    u += 0x7FFFu + ((u >> 16) & 1u);   // RNE
    return (unsigned short)(u >> 16);
}

// grid.x = 2048 (Aneg rows) + 2048 (Apos rows) + 320 (Wt tiles)
__global__ __launch_bounds__(256) void convert(
    const float* __restrict__ pl, const float* __restrict__ pg,
    const float* __restrict__ nl, const float* __restrict__ ng,
    const float* __restrict__ W1,
    unsigned short* __restrict__ Aneg, unsigned short* __restrict__ Apos,
    unsigned short* __restrict__ Wt, unsigned int* __restrict__ counter)
{
    const int b = blockIdx.x, tid = threadIdx.x;
    if (b == 0 && tid == 0) *counter = 0u;   // reset ticket each call
    if (b < 4096) {
        const int m = (b < 2048) ? b : b - 2048;
        const float* lo = (b < 2048) ? nl : pl;
        const float* hi = (b < 2048) ? ng : pg;
        unsigned short* dst = (b < 2048) ? Aneg : Apos;
        const int kq = tid * 4;
        const float4 v = (kq < XD) ? *(const float4*)(lo + m * XD + kq)
                                   : *(const float4*)(hi + m * XD + kq - XD);
        ushort4 o;
        o.x = f2bf(v.x); o.y = f2bf(v.y); o.z = f2bf(v.z); o.w = f2bf(v.w);
        *(ushort4*)(dst + m * KTOT + kq) = o;
    } else {
        // W1 [1024][300] -> Wt [320][1024] bf16, zero-padded rows 300..319
        __shared__ unsigned short ts[16][72];
        const int t = b - 4096;
        const int nt = t % 20, kt = t / 20;   // 20 n-tiles x 16 k-tiles
        const int n = nt * 16 + (tid & 15);
        const int kl = tid >> 4;
        #pragma unroll
        for (int j = 0; j < 4; ++j) {
            const int k = kt * 64 + kl * 4 + j;
            const float val = (n < HID) ? W1[k * HID + n] : 0.f;
            ts[tid & 15][kl * 4 + j] = f2bf(val);
        }
        __syncthreads();
        const int nw = tid >> 4, kw = (tid & 15) * 4;
        ushort4 o;
        o.x = ts[nw][kw]; o.y = ts[nw][kw + 1]; o.z = ts[nw][kw + 2]; o.w = ts[nw][kw + 3];
        *(ushort4*)(Wt + (nt * 16 + nw) * KTOT + kt * 64 + kw) = o;
    }
}

// One wave per block, 32x32 tile of 16x16x32 MFMAs, all jobs K=512.
// job 0: LP4  = nl @ W1l               (k<512,  scattered [k/4][l][4])
// job 1: GPB  = ng @ W1g + b1          (k>=512)
// job 2: P0a  = pl @ W1l               (k<512,  raw)
// job 3: P0b  = pg @ W1g               (k>=512, raw)
__global__ __launch_bounds__(64) void mfma_gemm(
    const unsigned short* __restrict__ Aneg, const unsigned short* __restrict__ Apos,
    const unsigned short* __restrict__ Wt, const float* __restrict__ b1,
    float* __restrict__ LP4, float* __restrict__ GPB,
    float* __restrict__ P0a, float* __restrict__ P0b)
{
    const int job = blockIdx.z;
    const int m0 = blockIdx.x * 32, n0 = blockIdx.y * 32;
    const int lane = threadIdx.x;
    const int r = lane & 15, g = lane >> 4;

    const unsigned short* A = (job >= 2) ? Apos : Aneg;
    const int kbeg = (job & 1) ? XD : 0;

    const unsigned short* a0p = A  + (m0 + r) * KTOT + kbeg + 8 * g;
    const unsigned short* a1p = a0p + 16 * KTOT;
    const unsigned short* b0p = Wt + (n0 + r) * KTOT + kbeg + 8 * g;
    const unsigned short* b1p = b0p + 16 * KTOT;

    f32x4 acc00 = {0,0,0,0}, acc01 = {0,0,0,0}, acc10 = {0,0,0,0}, acc11 = {0,0,0,0};

    #pragma unroll 8
    for (int k = 0; k < XD; k += 32) {
        const bf16x8 a0 = *(const bf16x8*)(a0p + k);
        const bf16x8 a1 = *(const bf16x8*)(a1p + k);
        const bf16x8 w0 = *(const bf16x8*)(b0p + k);
        const bf16x8 w1 = *(const bf16x8*)(b1p + k);
        acc00 = __builtin_amdgcn_mfma_f32_16x16x32_bf16(a0, w0, acc00, 0, 0, 0);
        acc01 = __builtin_amdgcn_mfma_f32_16x16x32_bf16(a0, w1, acc01, 0, 0, 0);
        acc10 = __builtin_amdgcn_mfma_f32_16x16x32_bf16(a1, w0, acc10, 0, 0, 0);
        acc11 = __builtin_amdgcn_mfma_f32_16x16x32_bf16(a1, w1, acc11, 0, 0, 0);
    }

    f32x4 accs[2][2] = {{acc00, acc01}, {acc10, acc11}};
    #pragma unroll
    for (int mi = 0; mi < 2; ++mi) {
        #pragma unroll
        for (int ni = 0; ni < 2; ++ni) {
            const int n = n0 + ni * 16 + r;
            const int mb = m0 + mi * 16 + 4 * g;
            const f32x4 v = accs[mi][ni];
            if (job == 0) {
                float* base = LP4 + ((size_t)(n >> 2) * NR + mb) * 4 + (n & 3);
                base[0] = v[0]; base[4] = v[1]; base[8] = v[2]; base[12] = v[3];
            } else if (n < HID) {
                const float bias = (job == 1) ? b1[n] : 0.f;
                float* out = (job == 1) ? GPB : ((job == 2) ? P0a : P0b);
                #pragma unroll
                for (int j = 0; j < 4; ++j)
                    out[(size_t)(mb + j) * GSTR + n] = v[j] + bias;
            }
        }
    }
}

// grid (32, 9): y<8 -> neg chunk=y, g-group of 8 = x
//               y==8 -> pos rows, 64 rows per block (thread = row x k-quarter)
// Last block (ticket) sums all partials -> out.
__global__ __launch_bounds__(256) void fused(
    const float* __restrict__ LP4, const float* __restrict__ GPB,
    const float* __restrict__ P0a, const float* __restrict__ P0b,
    const float* __restrict__ b1, const float* __restrict__ W2,
    const float* __restrict__ b2,
    float* __restrict__ partials, unsigned int* __restrict__ counter,
    float* __restrict__ out)
{
    __shared__ float gbs[8][HID];
    __shared__ float w2s[HID];
    __shared__ float red[4][8];
    __shared__ int sh_last;
    const int tid = threadIdx.x;
    const int bx = blockIdx.x, by = blockIdx.y;
    const int bid = by * 32 + bx;
    const int wid = tid >> 6;
    float partial = 0.f;

    if (by < 8) {
        const int chunk = by, g0 = bx * 8;
        for (int idx = tid; idx < 8 * HID; idx += 256) {
            const int gt = idx / HID, k = idx - gt * HID;
            gbs[gt][k] = GPB[(size_t)(chunk * BS + g0 + gt) * GSTR + k];
        }
        for (int idx = tid; idx < HID; idx += 256) w2s[idx] = W2[idx];
        __syncthreads();

        const int lg = chunk * BS + tid;
        const float4* lp4 = (const float4*)LP4 + lg;
        float acc[8] = {0.f,0.f,0.f,0.f,0.f,0.f,0.f,0.f};
        // 2-deep software pipeline on LP (indices up to 76 stay inside the
        // 80-slot padded LP4 -> always valid memory).
        float4 lp_0 = lp4[0];
        float4 lp_1 = lp4[(size_t)1 * NR];
        for (int k4 = 0; k4 < HID / 4; ++k4) {
            const float4 lp_n = lp4[(size_t)(k4 + 2) * NR];
            const float4 w4 = *(const float4*)&w2s[k4 * 4];
            #pragma unroll
            for (int gt = 0; gt < 8; ++gt) {
                const float4 g4 = *(const float4*)&gbs[gt][k4 * 4];
                acc[gt] = fmaf(fmaxf(g4.x + lp_0.x, 0.f), w4.x, acc[gt]);
                acc[gt] = fmaf(fmaxf(g4.y + lp_0.y, 0.f), w4.y, acc[gt]);
                acc[gt] = fmaf(fmaxf(g4.z + lp_0.z, 0.f), w4.z, acc[gt]);
                acc[gt] = fmaf(fmaxf(g4.w + lp_0.w, 0.f), w4.w, acc[gt]);
            }
            lp_0 = lp_1; lp_1 = lp_n;
        }

        const float b2v = b2[0];
        // s bounded (softplus of small dot) -> exp never overflows fp32; skip max pass.
        #pragma unroll
        for (int gt = 0; gt < 8; ++gt) {
            float e = __expf(softplus_f(acc[gt] + b2v));
            #pragma unroll
            for (int o = 32; o > 0; o >>= 1) e += __shfl_xor(e, o);
            if ((tid & 63) == 0) red[wid][gt] = e;
        }
        __syncthreads();
        partial = 0.f;
        #pragma unroll
        for (int gt = 0; gt < 8; ++gt)
            partial += __logf(red[0][gt] + red[1][gt] + red[2][gt] + red[3][gt]);
    } else {
        // pos: 64 rows per block; thread = (row, k-quarter)
        for (int idx = tid; idx < HID; idx += 256) {
            w2s[idx] = W2[idx];
            gbs[0][idx] = b1[idx];
        }
        __syncthreads();
        const int rl = tid >> 2, q = tid & 3;
        const int i = bx * 64 + rl;
        const int q0 = q * 19;
        const int q1 = (q == 3) ? HID / 4 : q0 + 19;
        const float4* ra = (const float4*)(P0a + (size_t)i * GSTR);
        const float4* rb = (const float4*)(P0b + (size_t)i * GSTR);
        float acc = 0.f;
        for (int k4 = q0; k4 < q1; ++k4) {
            const float4 a = ra[k4], b = rb[k4];
            const float4 bb = *(const float4*)&gbs[0][k4 * 4];
            const float4 wv = *(const float4*)&w2s[k4 * 4];
            acc += fmaxf(a.x + b.x + bb.x, 0.f) * wv.x
                 + fmaxf(a.y + b.y + bb.y, 0.f) * wv.y
                 + fmaxf(a.z + b.z + bb.z, 0.f) * wv.z
                 + fmaxf(a.w + b.w + bb.w, 0.f) * wv.w;
        }
        acc += __shfl_xor(acc, 1);
        acc += __shfl_xor(acc, 2);
        float sp = (q == 0) ? softplus_f(acc + b2[0]) : 0.f;
        #pragma unroll
        for (int o = 32; o > 0; o >>= 1) sp += __shfl_xor(sp, o);
        if ((tid & 63) == 0) red[wid][0] = sp;
        __syncthreads();
        partial = -(red[0][0] + red[1][0] + red[2][0] + red[3][0]);
    }

    // ---- last-block finalize (device-scope ticket) ----
    if (tid == 0) {
        partials[bid] = partial;
        __threadfence();
        const unsigned t = atomicAdd(counter, 1u);
        sh_last = (t == NBLK - 1) ? 1 : 0;
    }
    __syncthreads();
    if (sh_last) {
        __threadfence();
        const volatile float* p = (const volatile float*)partials;
        float v = p[tid];
        if (tid + 256 < NBLK) v += p[tid + 256];
        #pragma unroll
        for (int o = 32; o > 0; o >>= 1) v += __shfl_xor(v, o);
        if ((tid & 63) == 0) red[wid][0] = v;
        __syncthreads();
        if (tid == 0)
            out[0] = (red[0][0] + red[1][0] + red[2][0] + red[3][0]) * (1.f / 2048.f);
    }
}

extern "C" void kernel_launch(void* const* d_in, const int* in_sizes, int n_in,
                              void* d_out, int out_size, void* d_ws, size_t ws_size,
                              hipStream_t stream)
{
    const float* pl = (const float*)d_in[0];
    const float* pg = (const float*)d_in[1];
    const float* nl = (const float*)d_in[2];
    const float* ng = (const float*)d_in[3];
    const float* W1 = (const float*)d_in[4];
    const float* b1 = (const float*)d_in[5];
    const float* W2 = (const float*)d_in[6];
    const float* b2 = (const float*)d_in[7];

    char* ws = (char*)d_ws;
    unsigned short* Aneg = (unsigned short*)(ws);                 // 4 MB
    unsigned short* Apos = (unsigned short*)(ws + (4u << 20));    // 4 MB
    unsigned short* Wt   = (unsigned short*)(ws + (8u << 20));    // 640 KB
    float* LP4  = (float*)(ws + (9u << 20));                      // 2.62 MB
    float* GPB  = (float*)(ws + (12u << 20));                     // 2.49 MB
    float* P0a  = (float*)(ws + (15u << 20));                     // 2.49 MB
    float* P0b  = (float*)(ws + (18u << 20));                     // 2.49 MB
    float* partials = (float*)(ws + (21u << 20));                 // 288 f
    unsigned int* counter = (unsigned int*)(ws + (21u << 20) + 4096);
    float* out = (float*)d_out;

    hipLaunchKernelGGL(convert, dim3(4096 + 320), dim3(256), 0, stream,
                       pl, pg, nl, ng, W1, Aneg, Apos, Wt, counter);
    hipLaunchKernelGGL(mfma_gemm, dim3(NR / 32, NPAD / 32, 4), dim3(64), 0, stream,
                       Aneg, Apos, Wt, b1, LP4, GPB, P0a, P0b);
    hipLaunchKernelGGL(fused, dim3(32, 9), dim3(256), 0, stream,
                       LP4, GPB, P0a, P0b, b1, W2, b2, partials, counter, out);
}

// Round 5
// 68.469 us; speedup vs baseline: 1.2285x; 1.1659x over previous
//
#include <hip/hip_runtime.h>
#include <math.h>

#define NR   2048
#define XD   512
#define HID  300
#define BS   256
#define NCH  8
#define NPAD 320          // HID padded to 32
#define KTOT 1024
#define GSTR 304          // row stride for GPB/P0a/P0b (float4-aligned)
#define NBLK 544          // fused grid: 512 neg + 32 pos

typedef __attribute__((ext_vector_type(8))) short bf16x8;
typedef __attribute__((ext_vector_type(4))) float f32x4;

__device__ __forceinline__ float softplus_f(float x) {
    return fmaxf(x, 0.f) + log1pf(__expf(-fabsf(x)));
}
__device__ __forceinline__ unsigned short f2bf(float f) {
    unsigned int u = __float_as_uint(f);
    u += 0x7FFFu + ((u >> 16) & 1u);   // RNE
    return (unsigned short)(u >> 16);
}

// grid.x = 2048 (Aneg rows) + 2048 (Apos rows) + 320 (Wt tiles)
__global__ __launch_bounds__(256) void convert(
    const float* __restrict__ pl, const float* __restrict__ pg,
    const float* __restrict__ nl, const float* __restrict__ ng,
    const float* __restrict__ W1,
    unsigned short* __restrict__ Aneg, unsigned short* __restrict__ Apos,
    unsigned short* __restrict__ Wt, unsigned int* __restrict__ counter)
{
    const int b = blockIdx.x, tid = threadIdx.x;
    if (b == 0 && tid == 0) *counter = 0u;   // reset ticket each call
    if (b < 4096) {
        const int m = (b < 2048) ? b : b - 2048;
        const float* lo = (b < 2048) ? nl : pl;
        const float* hi = (b < 2048) ? ng : pg;
        unsigned short* dst = (b < 2048) ? Aneg : Apos;
        const int kq = tid * 4;
        const float4 v = (kq < XD) ? *(const float4*)(lo + m * XD + kq)
                                   : *(const float4*)(hi + m * XD + kq - XD);
        ushort4 o;
        o.x = f2bf(v.x); o.y = f2bf(v.y); o.z = f2bf(v.z); o.w = f2bf(v.w);
        *(ushort4*)(dst + m * KTOT + kq) = o;
    } else {
        // W1 [1024][300] -> Wt [320][1024] bf16, zero-padded rows 300..319
        __shared__ unsigned short ts[16][72];
        const int t = b - 4096;
        const int nt = t % 20, kt = t / 20;   // 20 n-tiles x 16 k-tiles
        const int n = nt * 16 + (tid & 15);
        const int kl = tid >> 4;
        #pragma unroll
        for (int j = 0; j < 4; ++j) {
            const int k = kt * 64 + kl * 4 + j;
            const float val = (n < HID) ? W1[k * HID + n] : 0.f;
            ts[tid & 15][kl * 4 + j] = f2bf(val);
        }
        __syncthreads();
        const int nw = tid >> 4, kw = (tid & 15) * 4;
        ushort4 o;
        o.x = ts[nw][kw]; o.y = ts[nw][kw + 1]; o.z = ts[nw][kw + 2]; o.w = ts[nw][kw + 3];
        *(ushort4*)(Wt + (nt * 16 + nw) * KTOT + kt * 64 + kw) = o;
    }
}

// One wave per block, 32x32 tile of 16x16x32 MFMAs, all jobs K=512.
// job 0: LP4  = nl @ W1l               (k<512,  scattered [k/4][l][4])
// job 1: GPB  = ng @ W1g + b1          (k>=512)
// job 2: P0a  = pl @ W1l               (k<512,  raw)
// job 3: P0b  = pg @ W1g               (k>=512, raw)
__global__ __launch_bounds__(64) void mfma_gemm(
    const unsigned short* __restrict__ Aneg, const unsigned short* __restrict__ Apos,
    const unsigned short* __restrict__ Wt, const float* __restrict__ b1,
    float* __restrict__ LP4, float* __restrict__ GPB,
    float* __restrict__ P0a, float* __restrict__ P0b)
{
    const int job = blockIdx.z;
    const int m0 = blockIdx.x * 32, n0 = blockIdx.y * 32;
    const int lane = threadIdx.x;
    const int r = lane & 15, g = lane >> 4;

    const unsigned short* A = (job >= 2) ? Apos : Aneg;
    const int kbeg = (job & 1) ? XD : 0;

    const unsigned short* a0p = A  + (m0 + r) * KTOT + kbeg + 8 * g;
    const unsigned short* a1p = a0p + 16 * KTOT;
    const unsigned short* b0p = Wt + (n0 + r) * KTOT + kbeg + 8 * g;
    const unsigned short* b1p = b0p + 16 * KTOT;

    f32x4 acc00 = {0,0,0,0}, acc01 = {0,0,0,0}, acc10 = {0,0,0,0}, acc11 = {0,0,0,0};

    #pragma unroll 8
    for (int k = 0; k < XD; k += 32) {
        const bf16x8 a0 = *(const bf16x8*)(a0p + k);
        const bf16x8 a1 = *(const bf16x8*)(a1p + k);
        const bf16x8 w0 = *(const bf16x8*)(b0p + k);
        const bf16x8 w1 = *(const bf16x8*)(b1p + k);
        acc00 = __builtin_amdgcn_mfma_f32_16x16x32_bf16(a0, w0, acc00, 0, 0, 0);
        acc01 = __builtin_amdgcn_mfma_f32_16x16x32_bf16(a0, w1, acc01, 0, 0, 0);
        acc10 = __builtin_amdgcn_mfma_f32_16x16x32_bf16(a1, w0, acc10, 0, 0, 0);
        acc11 = __builtin_amdgcn_mfma_f32_16x16x32_bf16(a1, w1, acc11, 0, 0, 0);
    }

    f32x4 accs[2][2] = {{acc00, acc01}, {acc10, acc11}};
    #pragma unroll
    for (int mi = 0; mi < 2; ++mi) {
        #pragma unroll
        for (int ni = 0; ni < 2; ++ni) {
            const int n = n0 + ni * 16 + r;
            const int mb = m0 + mi * 16 + 4 * g;
            const f32x4 v = accs[mi][ni];
            if (job == 0) {
                float* base = LP4 + ((size_t)(n >> 2) * NR + mb) * 4 + (n & 3);
                base[0] = v[0]; base[4] = v[1]; base[8] = v[2]; base[12] = v[3];
            } else if (n < HID) {
                const float bias = (job == 1) ? b1[n] : 0.f;
                float* out = (job == 1) ? GPB : ((job == 2) ? P0a : P0b);
                #pragma unroll
                for (int j = 0; j < 4; ++j)
                    out[(size_t)(mb + j) * GSTR + n] = v[j] + bias;
            }
        }
    }
}

// grid (544): bid<512 -> neg, chunk = bid>>6, g-group of 4 = bid&63, thread = l
//             bid>=512 -> pos, 64 rows per block (thread = row x k-quarter)
// Last block (ticket) sums all partials -> out.
__global__ __launch_bounds__(256) void fused(
    const float* __restrict__ LP4, const float* __restrict__ GPB,
    const float* __restrict__ P0a, const float* __restrict__ P0b,
    const float* __restrict__ b1, const float* __restrict__ W2,
    const float* __restrict__ b2,
    float* __restrict__ partials, unsigned int* __restrict__ counter,
    float* __restrict__ out)
{
    __shared__ float w2s[HID];
    __shared__ float b1s[HID];
    __shared__ float red[4][4];
    __shared__ int sh_last;
    const int tid = threadIdx.x;
    const int bid = blockIdx.x;
    const int wid = tid >> 6;
    float partial = 0.f;

    if (bid < 512) {
        // ---- negative term: 4 g-rows, uniform data via scalar loads ----
        const int chunk = bid >> 6;
        const int g0 = (bid & 63) * 4;
        const float* gp = GPB + (size_t)(chunk * BS + g0) * GSTR;
        const int lg = chunk * BS + tid;
        const float4* lp4 = (const float4*)LP4 + lg;

        float acc[4] = {0.f, 0.f, 0.f, 0.f};
        float4 a0 = lp4[0];
        float4 a1 = lp4[(size_t)NR];
        for (int k8 = 0; k8 < 37; ++k8) {
            const int k = k8 * 8;
            const float4 n0 = lp4[(size_t)(2 * k8 + 2) * NR];
            const float4 n1 = lp4[(size_t)(2 * k8 + 3) * NR];
            const float4 wa = *(const float4*)(W2 + k);       // uniform -> s_load
            const float4 wb = *(const float4*)(W2 + k + 4);
            #pragma unroll
            for (int gt = 0; gt < 4; ++gt) {
                const float* gr = gp + gt * GSTR + k;         // uniform -> s_load
                const float4 ga = *(const float4*)(gr);
                const float4 gb = *(const float4*)(gr + 4);
                acc[gt] = fmaf(fmaxf(ga.x + a0.x, 0.f), wa.x, acc[gt]);
                acc[gt] = fmaf(fmaxf(ga.y + a0.y, 0.f), wa.y, acc[gt]);
                acc[gt] = fmaf(fmaxf(ga.z + a0.z, 0.f), wa.z, acc[gt]);
                acc[gt] = fmaf(fmaxf(ga.w + a0.w, 0.f), wa.w, acc[gt]);
                acc[gt] = fmaf(fmaxf(gb.x + a1.x, 0.f), wb.x, acc[gt]);
                acc[gt] = fmaf(fmaxf(gb.y + a1.y, 0.f), wb.y, acc[gt]);
                acc[gt] = fmaf(fmaxf(gb.z + a1.z, 0.f), wb.z, acc[gt]);
                acc[gt] = fmaf(fmaxf(gb.w + a1.w, 0.f), wb.w, acc[gt]);
            }
            a0 = n0; a1 = n1;
        }
        {   // tail k = 296..299 (uses a0 = k4 index 74)
            const float4 wt = *(const float4*)(W2 + 296);
            #pragma unroll
            for (int gt = 0; gt < 4; ++gt) {
                const float4 ga = *(const float4*)(gp + gt * GSTR + 296);
                acc[gt] = fmaf(fmaxf(ga.x + a0.x, 0.f), wt.x, acc[gt]);
                acc[gt] = fmaf(fmaxf(ga.y + a0.y, 0.f), wt.y, acc[gt]);
                acc[gt] = fmaf(fmaxf(ga.z + a0.z, 0.f), wt.z, acc[gt]);
                acc[gt] = fmaf(fmaxf(ga.w + a0.w, 0.f), wt.w, acc[gt]);
            }
        }

        const float b2v = b2[0];
        // s bounded (softplus of small dot) -> exp never overflows fp32; skip max pass.
        #pragma unroll
        for (int gt = 0; gt < 4; ++gt) {
            float e = __expf(softplus_f(acc[gt] + b2v));
            #pragma unroll
            for (int o = 32; o > 0; o >>= 1) e += __shfl_xor(e, o);
            if ((tid & 63) == 0) red[wid][gt] = e;
        }
        __syncthreads();
        partial = 0.f;
        #pragma unroll
        for (int gt = 0; gt < 4; ++gt)
            partial += __logf(red[0][gt] + red[1][gt] + red[2][gt] + red[3][gt]);
    } else {
        // ---- positive term: 64 rows per block; thread = (row, k-quarter) ----
        for (int idx = tid; idx < HID; idx += 256) {
            w2s[idx] = W2[idx];
            b1s[idx] = b1[idx];
        }
        __syncthreads();
        const int rl = tid >> 2, q = tid & 3;
        const int i = (bid - 512) * 64 + rl;
        const int q0 = q * 19;
        const int q1 = (q == 3) ? HID / 4 : q0 + 19;
        const float4* ra = (const float4*)(P0a + (size_t)i * GSTR);
        const float4* rb = (const float4*)(P0b + (size_t)i * GSTR);
        float acc = 0.f;
        for (int k4 = q0; k4 < q1; ++k4) {
            const float4 a = ra[k4], b = rb[k4];
            const float4 bb = *(const float4*)&b1s[k4 * 4];
            const float4 wv = *(const float4*)&w2s[k4 * 4];
            acc += fmaxf(a.x + b.x + bb.x, 0.f) * wv.x
                 + fmaxf(a.y + b.y + bb.y, 0.f) * wv.y
                 + fmaxf(a.z + b.z + bb.z, 0.f) * wv.z
                 + fmaxf(a.w + b.w + bb.w, 0.f) * wv.w;
        }
        acc += __shfl_xor(acc, 1);
        acc += __shfl_xor(acc, 2);
        float sp = (q == 0) ? softplus_f(acc + b2[0]) : 0.f;
        #pragma unroll
        for (int o = 32; o > 0; o >>= 1) sp += __shfl_xor(sp, o);
        if ((tid & 63) == 0) red[wid][0] = sp;
        __syncthreads();
        partial = -(red[0][0] + red[1][0] + red[2][0] + red[3][0]);
    }

    // ---- last-block finalize (device-scope ticket) ----
    if (tid == 0) {
        partials[bid] = partial;
        __threadfence();
        const unsigned t = atomicAdd(counter, 1u);
        sh_last = (t == NBLK - 1) ? 1 : 0;
    }
    __syncthreads();
    if (sh_last) {
        __threadfence();
        const volatile float* p = (const volatile float*)partials;
        float v = p[tid] + p[tid + 256];
        if (tid + 512 < NBLK) v += p[tid + 512];
        #pragma unroll
        for (int o = 32; o > 0; o >>= 1) v += __shfl_xor(v, o);
        if ((tid & 63) == 0) red[wid][0] = v;
        __syncthreads();
        if (tid == 0)
            out[0] = (red[0][0] + red[1][0] + red[2][0] + red[3][0]) * (1.f / 2048.f);
    }
}

extern "C" void kernel_launch(void* const* d_in, const int* in_sizes, int n_in,
                              void* d_out, int out_size, void* d_ws, size_t ws_size,
                              hipStream_t stream)
{
    const float* pl = (const float*)d_in[0];
    const float* pg = (const float*)d_in[1];
    const float* nl = (const float*)d_in[2];
    const float* ng = (const float*)d_in[3];
    const float* W1 = (const float*)d_in[4];
    const float* b1 = (const float*)d_in[5];
    const float* W2 = (const float*)d_in[6];
    const float* b2 = (const float*)d_in[7];

    char* ws = (char*)d_ws;
    unsigned short* Aneg = (unsigned short*)(ws);                 // 4 MB
    unsigned short* Apos = (unsigned short*)(ws + (4u << 20));    // 4 MB
    unsigned short* Wt   = (unsigned short*)(ws + (8u << 20));    // 640 KB
    float* LP4  = (float*)(ws + (9u << 20));                      // 2.62 MB
    float* GPB  = (float*)(ws + (12u << 20));                     // 2.49 MB
    float* P0a  = (float*)(ws + (15u << 20));                     // 2.49 MB
    float* P0b  = (float*)(ws + (18u << 20));                     // 2.49 MB
    float* partials = (float*)(ws + (21u << 20));                 // 544 f
    unsigned int* counter = (unsigned int*)(ws + (21u << 20) + 4096);
    float* out = (float*)d_out;

    hipLaunchKernelGGL(convert, dim3(4096 + 320), dim3(256), 0, stream,
                       pl, pg, nl, ng, W1, Aneg, Apos, Wt, counter);
    hipLaunchKernelGGL(mfma_gemm, dim3(NR / 32, NPAD / 32, 4), dim3(64), 0, stream,
                       Aneg, Apos, Wt, b1, LP4, GPB, P0a, P0b);
    hipLaunchKernelGGL(fused, dim3(NBLK), dim3(256), 0, stream,
                       LP4, GPB, P0a, P0b, b1, W2, b2, partials, counter, out);
}

// Round 6
// 66.411 us; speedup vs baseline: 1.2666x; 1.0310x over previous
//
#include <hip/hip_runtime.h>
#include <math.h>

#define NR   2048
#define XD   512
#define HID  300
#define BS   256
#define NCH  8
#define NPAD 320          // HID padded to 32
#define KTOT 1024
#define GSTR 304          // row stride for GPB/P0a/P0b (float4-aligned)
#define NBLK 544          // fused grid: 512 neg + 32 pos

typedef __attribute__((ext_vector_type(8))) short bf16x8;
typedef __attribute__((ext_vector_type(4))) float f32x4;

__device__ __forceinline__ float softplus_f(float x) {
    return fmaxf(x, 0.f) + log1pf(__expf(-fabsf(x)));
}
__device__ __forceinline__ unsigned short f2bf(float f) {
    unsigned int u = __float_as_uint(f);
    u += 0x7FFFu + ((u >> 16) & 1u);   // RNE
    return (unsigned short)(u >> 16);
}

// grid.x = 2048 (Aneg rows) + 2048 (Apos rows) + 320 (Wt tiles)
__global__ __launch_bounds__(256) void convert(
    const float* __restrict__ pl, const float* __restrict__ pg,
    const float* __restrict__ nl, const float* __restrict__ ng,
    const float* __restrict__ W1,
    unsigned short* __restrict__ Aneg, unsigned short* __restrict__ Apos,
    unsigned short* __restrict__ Wt, unsigned int* __restrict__ counter)
{
    const int b = blockIdx.x, tid = threadIdx.x;
    if (b == 0 && tid == 0) *counter = 0u;   // reset ticket each call
    if (b < 4096) {
        const int m = (b < 2048) ? b : b - 2048;
        const float* lo = (b < 2048) ? nl : pl;
        const float* hi = (b < 2048) ? ng : pg;
        unsigned short* dst = (b < 2048) ? Aneg : Apos;
        const int kq = tid * 4;
        const float4 v = (kq < XD) ? *(const float4*)(lo + m * XD + kq)
                                   : *(const float4*)(hi + m * XD + kq - XD);
        ushort4 o;
        o.x = f2bf(v.x); o.y = f2bf(v.y); o.z = f2bf(v.z); o.w = f2bf(v.w);
        *(ushort4*)(dst + m * KTOT + kq) = o;
    } else {
        // W1 [1024][300] -> Wt [320][1024] bf16, zero-padded rows 300..319
        __shared__ unsigned short ts[16][72];
        const int t = b - 4096;
        const int nt = t % 20, kt = t / 20;   // 20 n-tiles x 16 k-tiles
        const int n = nt * 16 + (tid & 15);
        const int kl = tid >> 4;
        #pragma unroll
        for (int j = 0; j < 4; ++j) {
            const int k = kt * 64 + kl * 4 + j;
            const float val = (n < HID) ? W1[k * HID + n] : 0.f;
            ts[tid & 15][kl * 4 + j] = f2bf(val);
        }
        __syncthreads();
        const int nw = tid >> 4, kw = (tid & 15) * 4;
        ushort4 o;
        o.x = ts[nw][kw]; o.y = ts[nw][kw + 1]; o.z = ts[nw][kw + 2]; o.w = ts[nw][kw + 3];
        *(ushort4*)(Wt + (nt * 16 + nw) * KTOT + kt * 64 + kw) = o;
    }
}

// One wave per block, 32x32 tile of 16x16x32 MFMAs, all jobs K=512.
// job 0: LP4  = nl @ W1l               (k<512,  scattered [k/4][l][4])
// job 1: GPB  = ng @ W1g + b1          (k>=512)
// job 2: P0a  = pl @ W1l               (k<512,  raw)
// job 3: P0b  = pg @ W1g               (k>=512, raw)
__global__ __launch_bounds__(64) void mfma_gemm(
    const unsigned short* __restrict__ Aneg, const unsigned short* __restrict__ Apos,
    const unsigned short* __restrict__ Wt, const float* __restrict__ b1,
    float* __restrict__ LP4, float* __restrict__ GPB,
    float* __restrict__ P0a, float* __restrict__ P0b)
{
    const int job = blockIdx.z;
    const int m0 = blockIdx.x * 32, n0 = blockIdx.y * 32;
    const int lane = threadIdx.x;
    const int r = lane & 15, g = lane >> 4;

    const unsigned short* A = (job >= 2) ? Apos : Aneg;
    const int kbeg = (job & 1) ? XD : 0;

    const unsigned short* a0p = A  + (m0 + r) * KTOT + kbeg + 8 * g;
    const unsigned short* a1p = a0p + 16 * KTOT;
    const unsigned short* b0p = Wt + (n0 + r) * KTOT + kbeg + 8 * g;
    const unsigned short* b1p = b0p + 16 * KTOT;

    f32x4 acc00 = {0,0,0,0}, acc01 = {0,0,0,0}, acc10 = {0,0,0,0}, acc11 = {0,0,0,0};

    #pragma unroll 8
    for (int k = 0; k < XD; k += 32) {
        const bf16x8 a0 = *(const bf16x8*)(a0p + k);
        const bf16x8 a1 = *(const bf16x8*)(a1p + k);
        const bf16x8 w0 = *(const bf16x8*)(b0p + k);
        const bf16x8 w1 = *(const bf16x8*)(b1p + k);
        acc00 = __builtin_amdgcn_mfma_f32_16x16x32_bf16(a0, w0, acc00, 0, 0, 0);
        acc01 = __builtin_amdgcn_mfma_f32_16x16x32_bf16(a0, w1, acc01, 0, 0, 0);
        acc10 = __builtin_amdgcn_mfma_f32_16x16x32_bf16(a1, w0, acc10, 0, 0, 0);
        acc11 = __builtin_amdgcn_mfma_f32_16x16x32_bf16(a1, w1, acc11, 0, 0, 0);
    }

    f32x4 accs[2][2] = {{acc00, acc01}, {acc10, acc11}};
    #pragma unroll
    for (int mi = 0; mi < 2; ++mi) {
        #pragma unroll
        for (int ni = 0; ni < 2; ++ni) {
            const int n = n0 + ni * 16 + r;
            const int mb = m0 + mi * 16 + 4 * g;
            const f32x4 v = accs[mi][ni];
            if (job == 0) {
                float* base = LP4 + ((size_t)(n >> 2) * NR + mb) * 4 + (n & 3);
                base[0] = v[0]; base[4] = v[1]; base[8] = v[2]; base[12] = v[3];
            } else if (n < HID) {
                const float bias = (job == 1) ? b1[n] : 0.f;
                float* out = (job == 1) ? GPB : ((job == 2) ? P0a : P0b);
                #pragma unroll
                for (int j = 0; j < 4; ++j)
                    out[(size_t)(mb + j) * GSTR + n] = v[j] + bias;
            }
        }
    }
}

// grid (544): bid<512 -> neg, chunk = bid>>6, g-group of 4 = bid&63, thread = l
//             bid>=512 -> pos, 64 rows per block (thread = row x k-quarter)
// Last block (ticket) sums all partials -> out.
__global__ __launch_bounds__(256) void fused(
    const float* __restrict__ LP4, const float* __restrict__ GPB,
    const float* __restrict__ P0a, const float* __restrict__ P0b,
    const float* __restrict__ b1, const float* __restrict__ W2,
    const float* __restrict__ b2,
    float* __restrict__ partials, unsigned int* __restrict__ counter,
    float* __restrict__ out)
{
    __shared__ __align__(16) float w2s[HID];
    __shared__ __align__(16) float gbs[4][HID];
    __shared__ float red[4][4];
    __shared__ int sh_last;
    const int tid = threadIdx.x;
    const int bid = blockIdx.x;
    const int wid = tid >> 6;
    float partial = 0.f;

    if (bid < 512) {
        // ---- negative term: 4 g-rows in LDS (broadcast reads are conflict-free) ----
        const int chunk = bid >> 6;
        const int g0 = (bid & 63) * 4;
        const float* gp = GPB + (size_t)(chunk * BS + g0) * GSTR;
        for (int idx = tid; idx < HID; idx += 256) {
            w2s[idx] = W2[idx];
            gbs[0][idx] = gp[idx];
            gbs[1][idx] = gp[GSTR + idx];
            gbs[2][idx] = gp[2 * GSTR + idx];
            gbs[3][idx] = gp[3 * GSTR + idx];
        }
        __syncthreads();

        const int lg = chunk * BS + tid;
        const float4* lp4 = (const float4*)LP4 + lg;

        float acc[4] = {0.f, 0.f, 0.f, 0.f};
        // 2-deep register pipeline on the per-lane LP stream (global/L2);
        // indices up to 75 stay inside the 80-slot padded LP4.
        float4 a0 = lp4[0];
        float4 a1 = lp4[(size_t)NR];
        for (int k8 = 0; k8 < 37; ++k8) {
            const int k = k8 * 8;
            const float4 n0 = lp4[(size_t)(2 * k8 + 2) * NR];
            const float4 n1 = lp4[(size_t)(2 * k8 + 3) * NR];
            const float4 wa = *(const float4*)&w2s[k];        // LDS broadcast
            const float4 wb = *(const float4*)&w2s[k + 4];
            #pragma unroll
            for (int gt = 0; gt < 4; ++gt) {
                const float4 ga = *(const float4*)&gbs[gt][k];
                const float4 gb = *(const float4*)&gbs[gt][k + 4];
                acc[gt] = fmaf(fmaxf(ga.x + a0.x, 0.f), wa.x, acc[gt]);
                acc[gt] = fmaf(fmaxf(ga.y + a0.y, 0.f), wa.y, acc[gt]);
                acc[gt] = fmaf(fmaxf(ga.z + a0.z, 0.f), wa.z, acc[gt]);
                acc[gt] = fmaf(fmaxf(ga.w + a0.w, 0.f), wa.w, acc[gt]);
                acc[gt] = fmaf(fmaxf(gb.x + a1.x, 0.f), wb.x, acc[gt]);
                acc[gt] = fmaf(fmaxf(gb.y + a1.y, 0.f), wb.y, acc[gt]);
                acc[gt] = fmaf(fmaxf(gb.z + a1.z, 0.f), wb.z, acc[gt]);
                acc[gt] = fmaf(fmaxf(gb.w + a1.w, 0.f), wb.w, acc[gt]);
            }
            a0 = n0; a1 = n1;
        }
        {   // tail k = 296..299 (uses a0 = k4 index 74)
            const float4 wt = *(const float4*)&w2s[296];
            #pragma unroll
            for (int gt = 0; gt < 4; ++gt) {
                const float4 ga = *(const float4*)&gbs[gt][296];
                acc[gt] = fmaf(fmaxf(ga.x + a0.x, 0.f), wt.x, acc[gt]);
                acc[gt] = fmaf(fmaxf(ga.y + a0.y, 0.f), wt.y, acc[gt]);
                acc[gt] = fmaf(fmaxf(ga.z + a0.z, 0.f), wt.z, acc[gt]);
                acc[gt] = fmaf(fmaxf(ga.w + a0.w, 0.f), wt.w, acc[gt]);
            }
        }

        const float b2v = b2[0];
        // s bounded (softplus of small dot) -> exp never overflows fp32; skip max pass.
        #pragma unroll
        for (int gt = 0; gt < 4; ++gt) {
            float e = __expf(softplus_f(acc[gt] + b2v));
            #pragma unroll
            for (int o = 32; o > 0; o >>= 1) e += __shfl_xor(e, o);
            if ((tid & 63) == 0) red[wid][gt] = e;
        }
        __syncthreads();
        partial = 0.f;
        #pragma unroll
        for (int gt = 0; gt < 4; ++gt)
            partial += __logf(red[0][gt] + red[1][gt] + red[2][gt] + red[3][gt]);
    } else {
        // ---- positive term: 64 rows per block; thread = (row, k-quarter) ----
        for (int idx = tid; idx < HID; idx += 256) {
            w2s[idx] = W2[idx];
            gbs[0][idx] = b1[idx];
        }
        __syncthreads();
        const int rl = tid >> 2, q = tid & 3;
        const int i = (bid - 512) * 64 + rl;
        const int q0 = q * 19;
        const int q1 = (q == 3) ? HID / 4 : q0 + 19;
        const float4* ra = (const float4*)(P0a + (size_t)i * GSTR);
        const float4* rb = (const float4*)(P0b + (size_t)i * GSTR);
        float acc = 0.f;
        for (int k4 = q0; k4 < q1; ++k4) {
            const float4 a = ra[k4], b = rb[k4];
            const float4 bb = *(const float4*)&gbs[0][k4 * 4];
            const float4 wv = *(const float4*)&w2s[k4 * 4];
            acc += fmaxf(a.x + b.x + bb.x, 0.f) * wv.x
                 + fmaxf(a.y + b.y + bb.y, 0.f) * wv.y
                 + fmaxf(a.z + b.z + bb.z, 0.f) * wv.z
                 + fmaxf(a.w + b.w + bb.w, 0.f) * wv.w;
        }
        acc += __shfl_xor(acc, 1);
        acc += __shfl_xor(acc, 2);
        float sp = (q == 0) ? softplus_f(acc + b2[0]) : 0.f;
        #pragma unroll
        for (int o = 32; o > 0; o >>= 1) sp += __shfl_xor(sp, o);
        if ((tid & 63) == 0) red[wid][0] = sp;
        __syncthreads();
        partial = -(red[0][0] + red[1][0] + red[2][0] + red[3][0]);
    }

    // ---- last-block finalize (device-scope ticket) ----
    if (tid == 0) {
        partials[bid] = partial;
        __threadfence();
        const unsigned t = atomicAdd(counter, 1u);
        sh_last = (t == NBLK - 1) ? 1 : 0;
    }
    __syncthreads();
    if (sh_last) {
        __threadfence();
        const volatile float* p = (const volatile float*)partials;
        float v = p[tid] + p[tid + 256];
        if (tid + 512 < NBLK) v += p[tid + 512];
        #pragma unroll
        for (int o = 32; o > 0; o >>= 1) v += __shfl_xor(v, o);
        if ((tid & 63) == 0) red[wid][0] = v;
        __syncthreads();
        if (tid == 0)
            out[0] = (red[0][0] + red[1][0] + red[2][0] + red[3][0]) * (1.f / 2048.f);
    }
}

extern "C" void kernel_launch(void* const* d_in, const int* in_sizes, int n_in,
                              void* d_out, int out_size, void* d_ws, size_t ws_size,
                              hipStream_t stream)
{
    const float* pl = (const float*)d_in[0];
    const float* pg = (const float*)d_in[1];
    const float* nl = (const float*)d_in[2];
    const float* ng = (const float*)d_in[3];
    const float* W1 = (const float*)d_in[4];
    const float* b1 = (const float*)d_in[5];
    const float* W2 = (const float*)d_in[6];
    const float* b2 = (const float*)d_in[7];

    char* ws = (char*)d_ws;
    unsigned short* Aneg = (unsigned short*)(ws);                 // 4 MB
    unsigned short* Apos = (unsigned short*)(ws + (4u << 20));    // 4 MB
    unsigned short* Wt   = (unsigned short*)(ws + (8u << 20));    // 640 KB
    float* LP4  = (float*)(ws + (9u << 20));                      // 2.62 MB
    float* GPB  = (float*)(ws + (12u << 20));                     // 2.49 MB
    float* P0a  = (float*)(ws + (15u << 20));                     // 2.49 MB
    float* P0b  = (float*)(ws + (18u << 20));                     // 2.49 MB
    float* partials = (float*)(ws + (21u << 20));                 // 544 f
    unsigned int* counter = (unsigned int*)(ws + (21u << 20) + 4096);
    float* out = (float*)d_out;

    hipLaunchKernelGGL(convert, dim3(4096 + 320), dim3(256), 0, stream,
                       pl, pg, nl, ng, W1, Aneg, Apos, Wt, counter);
    hipLaunchKernelGGL(mfma_gemm, dim3(NR / 32, NPAD / 32, 4), dim3(64), 0, stream,
                       Aneg, Apos, Wt, b1, LP4, GPB, P0a, P0b);
    hipLaunchKernelGGL(fused, dim3(NBLK), dim3(256), 0, stream,
                       LP4, GPB, P0a, P0b, b1, W2, b2, partials, counter, out);
}